// Round 1
// baseline (465.533 us; speedup 1.0000x reference)
//
#include <hip/hip_runtime.h>

typedef _Float16 half8 __attribute__((ext_vector_type(8)));
typedef float floatx4 __attribute__((ext_vector_type(4)));

#define DEVI __device__ __forceinline__

namespace {
constexpr int C_   = 256;
constexpr int DHW_ = 8192;
constexpr int N_   = 16384;   // rows = B*D*H*W
constexpr int NE_  = 8192;    // codebook entries
constexpr int K_   = 256;     // embedding dim

constexpr size_t LOSS_OFF  = 4194304;
constexpr size_t PERP_OFF  = 4194305;
constexpr size_t ENC_OFF   = 4194306;
constexpr size_t ENC_N     = 134217728ull;
constexpr size_t IDX_OFF   = ENC_OFF + ENC_N;
constexpr size_t ENC_BYTES = ENC_N * 4ull;   // 512 MiB

// scratch inside enc-region tail (wiped by the enc memset AFTER last use)
constexpr size_t SCR_ZH   = 480ull << 20;  // 16384x256 f16 = 8 MiB
constexpr size_t SCR_ZL   = 488ull << 20;  // 8 MiB
constexpr size_t SCR_EH   = 496ull << 20;  // 8192x256 f16 = 4 MiB
constexpr size_t SCR_EL   = 500ull << 20;  // 4 MiB
constexpr size_t SCR_ZZ   = 504ull << 20;  // 16384 f32
constexpr size_t SCR_KEY  = 505ull << 20;  // 16384 u64
constexpr size_t SCR_PART = 506ull << 20;  // loss partials f32

constexpr int NLOSS_BLOCKS = 2048;
}

// ---------------- init keys ----------------
__global__ void vq_init_keys(unsigned long long* __restrict__ keys) {
    int n = blockIdx.x * 256 + threadIdx.x;
    keys[n] = ~0ull;
}

// ---------------- split z -> ZH/ZL (f16) + zz (f32) ----------------
// z layout [B=2][C=256][DHW=8192]; zf[n][c] = z[b][c][dhw], n = b*DHW+dhw
__global__ void vq_split_z(const float* __restrict__ z,
                           _Float16* __restrict__ ZH, _Float16* __restrict__ ZL,
                           float* __restrict__ zz) {
    __shared__ float tile[64][260];
    int n0 = blockIdx.x * 64;
    int b  = n0 >> 13;           // n0 / DHW_
    int d0 = n0 & 8191;
    const float* zb = z + (size_t)b * C_ * DHW_ + d0;
    int t  = threadIdx.x;
    int nl = t & 63, cg = t >> 6;
    for (int cc = 0; cc < 256; cc += 4) {
        int c = cc + cg;
        tile[nl][c] = zb[(size_t)c * DHW_ + nl];   // coalesced over nl
    }
    __syncthreads();
    // write split arrays coalesced (t == c)
    for (int r = 0; r < 64; ++r) {
        float v = tile[r][t];
        _Float16 h = (_Float16)v;
        _Float16 l = (_Float16)((v - (float)h) * 2048.0f);  // residual scaled 2^11
        size_t o = (size_t)(n0 + r) * K_ + t;
        ZH[o] = h;
        ZL[o] = l;
    }
    // zz: numpy-pairwise order (256 = 128+128, 8 accumulators each).
    // Only the binade of zz matters for argmin equivalence, but replicate anyway.
    if (t < 64) {
        float tot[2];
        for (int h = 0; h < 2; ++h) {
            float r8[8];
            #pragma unroll
            for (int k = 0; k < 8; ++k) { float x = tile[t][h*128 + k]; r8[k] = x * x; }
            for (int i = 8; i < 128; i += 8) {
                #pragma unroll
                for (int k = 0; k < 8; ++k) { float x = tile[t][h*128 + i + k]; r8[k] += x * x; }
            }
            tot[h] = ((r8[0]+r8[1]) + (r8[2]+r8[3])) + ((r8[4]+r8[5]) + (r8[6]+r8[7]));
        }
        zz[n0 + t] = tot[0] + tot[1];
    }
}

// ---------------- split codebook -> EH/EL (f16, scaled) ----------------
__global__ void vq_split_e(const float* __restrict__ cb,
                           _Float16* __restrict__ EH, _Float16* __restrict__ EL) {
    int j0 = blockIdx.x * 64;
    int t  = threadIdx.x;   // t == c
    for (int i = 0; i < 64; ++i) {
        size_t o = (size_t)(j0 + i) * K_ + t;
        float v = cb[o] * 65536.0f;             // exact (pow2)
        _Float16 h = (_Float16)v;
        _Float16 l = (_Float16)((v - (float)h) * 2048.0f);  // exact residual, scaled
        EH[o] = h;
        EL[o] = l;
    }
}

// ---------------- GEMM + fused argmin ----------------
// dot = acc_a*2^-16 + acc_b*2^-27 ; d = fl(zz - 2*dot) ; argmin (tie -> min j)
#define TM 128
#define TN 128
#define KC 64

DEVI void stage_tile(const _Float16* __restrict__ g, _Float16* s, int t) {
    // tile: 128 rows x 64 halfs (128 B/row); XOR-swizzle on the GLOBAL side,
    // linear LDS dest (global_load_lds requirement), inverse XOR on ds_read.
    #pragma unroll
    for (int i = 0; i < 4; ++i) {
        int flat = i * 256 + t;
        int row  = flat >> 3;
        int sub  = flat & 7;
        int kb   = (sub * 16) ^ ((row & 7) * 16);
        const char* gp = (const char*)g + (size_t)row * (K_ * 2) + kb;
        char* lp = (char*)s + (size_t)flat * 16;
        __builtin_amdgcn_global_load_lds((const __attribute__((address_space(1))) void*)gp,
                                         (__attribute__((address_space(3))) void*)lp,
                                         16, 0, 0);
    }
}

__launch_bounds__(256, 2)
__global__ void vq_gemm_argmin(const _Float16* __restrict__ ZH, const _Float16* __restrict__ ZL,
                               const _Float16* __restrict__ EH, const _Float16* __restrict__ EL,
                               const float* __restrict__ zz,
                               unsigned long long* __restrict__ keys) {
    __shared__ _Float16 sZH[TM * KC], sZL[TM * KC], sEH[TN * KC], sEL[TN * KC];
    __shared__ unsigned long long rowmin[TM];

    int bid = blockIdx.x;
    int bm = bid & 127, bn = bid >> 7;
    int m0 = bm * TM, n0v = bn * TN;
    int t = threadIdx.x;
    int lane = t & 63, wid = t >> 6;
    int wm = wid >> 1, wn = wid & 1;      // 2x2 waves of 64x64

    floatx4 acc_a[4][4], acc_b[4][4];
    #pragma unroll
    for (int i = 0; i < 4; ++i)
        #pragma unroll
        for (int j = 0; j < 4; ++j) {
            acc_a[i][j] = (floatx4){0.f, 0.f, 0.f, 0.f};
            acc_b[i][j] = (floatx4){0.f, 0.f, 0.f, 0.f};
        }

    int g = lane >> 4, rr = lane & 15;

    for (int kc = 0; kc < 4; ++kc) {
        stage_tile(ZH + (size_t)m0 * K_ + kc * KC, sZH, t);
        stage_tile(ZL + (size_t)m0 * K_ + kc * KC, sZL, t);
        stage_tile(EH + (size_t)n0v * K_ + kc * KC, sEH, t);
        stage_tile(EL + (size_t)n0v * K_ + kc * KC, sEL, t);
        __syncthreads();

        #pragma unroll
        for (int ks = 0; ks < 2; ++ks) {
            half8 azh[4], azl[4], beh[4], bel[4];
            #pragma unroll
            for (int f = 0; f < 4; ++f) {
                int row = wm * 64 + f * 16 + rr;
                int p = (ks * 64 + g * 16) ^ ((row & 7) * 16);
                azh[f] = *(const half8*)((const char*)sZH + row * 128 + p);
                azl[f] = *(const half8*)((const char*)sZL + row * 128 + p);
                int col = wn * 64 + f * 16 + rr;
                int q = (ks * 64 + g * 16) ^ ((col & 7) * 16);
                beh[f] = *(const half8*)((const char*)sEH + col * 128 + q);
                bel[f] = *(const half8*)((const char*)sEL + col * 128 + q);
            }
            #pragma unroll
            for (int fi = 0; fi < 4; ++fi)
                #pragma unroll
                for (int fj = 0; fj < 4; ++fj) {
                    acc_a[fi][fj] = __builtin_amdgcn_mfma_f32_16x16x32_f16(azh[fi], beh[fj], acc_a[fi][fj], 0, 0, 0);
                    acc_b[fi][fj] = __builtin_amdgcn_mfma_f32_16x16x32_f16(azl[fi], beh[fj], acc_b[fi][fj], 0, 0, 0);
                    acc_b[fi][fj] = __builtin_amdgcn_mfma_f32_16x16x32_f16(azh[fi], bel[fj], acc_b[fi][fj], 0, 0, 0);
                }
        }
        __syncthreads();
    }

    if (t < TM) rowmin[t] = ~0ull;
    __syncthreads();

    constexpr float S_A = 1.0f / 65536.0f;       // 2^-16
    constexpr float S_B = 1.0f / 134217728.0f;   // 2^-27
    #pragma unroll
    for (int fi = 0; fi < 4; ++fi) {
        #pragma unroll
        for (int r = 0; r < 4; ++r) {
            int rowl = wm * 64 + fi * 16 + g * 4 + r;
            float zzv = zz[m0 + rowl];
            unsigned long long best = ~0ull;
            #pragma unroll
            for (int fj = 0; fj < 4; ++fj) {
                float dot = acc_a[fi][fj][r] * S_A + acc_b[fi][fj][r] * S_B;
                float d = zzv - 2.0f * dot;              // replicates ref fl(zz - fl(2*dot))
                unsigned int db = __float_as_uint(d);    // d > 0 always -> bits order == float order
                unsigned int jg = (unsigned)(n0v + wn * 64 + fj * 16 + rr);
                unsigned long long key = ((unsigned long long)db << 32) | jg;
                if (key < best) best = key;
            }
            atomicMin(&rowmin[rowl], best);
        }
    }
    __syncthreads();
    if (t < TM) atomicMin(&keys[m0 + t], rowmin[t]);
}

// ---------------- finalize idx ----------------
__global__ void vq_finalize_idx(const unsigned long long* __restrict__ keys,
                                float* __restrict__ out_idx) {
    int n = blockIdx.x * 256 + threadIdx.x;
    out_idx[n] = (float)(unsigned)(keys[n] & 0xFFFFFFFFull);
}

// ---------------- z_q (straight-through) + loss partials ----------------
__global__ void vq_zq_loss(const float* __restrict__ z, const float* __restrict__ cb,
                           const float* __restrict__ idxf, float* __restrict__ out0,
                           float* __restrict__ parts) {
    size_t i0 = ((size_t)blockIdx.x * 256 + threadIdx.x) * 8;
    int c   = (int)((i0 >> 13) & 255);
    int b   = (int)(i0 >> 21);
    int dhw = (int)(i0 & 8191);
    int nb  = b * DHW_ + dhw;
    float ls = 0.f;
    #pragma unroll
    for (int e = 0; e < 8; ++e) {
        int j = (int)idxf[nb + e];
        float zq = cb[(size_t)j * K_ + c];
        float zt = z[i0 + e];
        float diff = zq - zt;        // fl, matches ref
        out0[i0 + e] = zt + diff;    // fl(z_t + fl(z_q - z_t))
        ls += diff * diff;
    }
    __shared__ float red[256];
    red[threadIdx.x] = ls;
    __syncthreads();
    for (int s = 128; s > 0; s >>= 1) {
        if (threadIdx.x < (unsigned)s) red[threadIdx.x] += red[threadIdx.x + s];
        __syncthreads();
    }
    if (threadIdx.x == 0) parts[blockIdx.x] = red[0];
}

// ---------------- loss + perplexity ----------------
__global__ void vq_finalize_scalars(const float* __restrict__ parts,
                                    const float* __restrict__ idxf,
                                    float* __restrict__ out) {
    __shared__ int hist[NE_];
    __shared__ double dred[256];
    int t = threadIdx.x;
    for (int i = t; i < NE_; i += 256) hist[i] = 0;
    __syncthreads();
    for (int i = t; i < N_; i += 256) atomicAdd(&hist[(int)idxf[i]], 1);
    __syncthreads();
    double ent = 0.0;
    for (int i = t; i < NE_; i += 256) {
        float em = (float)hist[i] * (1.0f / 16384.0f);   // exact (pow2)
        float term = em * logf(em + 1e-10f);
        ent += (double)term;
    }
    dred[t] = ent;
    __syncthreads();
    for (int s = 128; s > 0; s >>= 1) {
        if (t < s) dred[t] += dred[t + s];
        __syncthreads();
    }
    double entr = 0.0;
    if (t == 0) entr = dred[0];
    __syncthreads();
    double ls = 0.0;
    for (int i = t; i < NLOSS_BLOCKS; i += 256) ls += (double)parts[i];
    dred[t] = ls;
    __syncthreads();
    for (int s = 128; s > 0; s >>= 1) {
        if (t < s) dred[t] += dred[t + s];
        __syncthreads();
    }
    if (t == 0) {
        double m = dred[0] / 4194304.0;
        float m1 = (float)m;
        out[LOSS_OFF] = m1 + 0.25f * m1;
        out[PERP_OFF] = (float)exp(-entr);
    }
}

// ---------------- scatter one-hot ----------------
__global__ void vq_scatter(const float* __restrict__ idxf, float* __restrict__ enc) {
    int n = blockIdx.x * 256 + threadIdx.x;
    int j = (int)idxf[n];
    enc[(size_t)n * NE_ + j] = 1.0f;
}

extern "C" void kernel_launch(void* const* d_in, const int* in_sizes, int n_in,
                              void* d_out, int out_size, void* d_ws, size_t ws_size,
                              hipStream_t stream) {
    const float* z  = (const float*)d_in[0];
    const float* cb = (const float*)d_in[1];
    float* out = (float*)d_out;

    char* encb = (char*)(out + ENC_OFF);
    _Float16* ZH = (_Float16*)(encb + SCR_ZH);
    _Float16* ZL = (_Float16*)(encb + SCR_ZL);
    _Float16* EH = (_Float16*)(encb + SCR_EH);
    _Float16* EL = (_Float16*)(encb + SCR_EL);
    float* zz = (float*)(encb + SCR_ZZ);
    unsigned long long* keys = (unsigned long long*)(encb + SCR_KEY);
    float* parts = (float*)(encb + SCR_PART);
    float* out_idx = out + IDX_OFF;
    float* enc = out + ENC_OFF;

    vq_init_keys<<<64, 256, 0, stream>>>(keys);
    vq_split_z<<<256, 256, 0, stream>>>(z, ZH, ZL, zz);
    vq_split_e<<<128, 256, 0, stream>>>(cb, EH, EL);
    vq_gemm_argmin<<<8192, 256, 0, stream>>>(ZH, ZL, EH, EL, zz, keys);
    vq_finalize_idx<<<64, 256, 0, stream>>>(keys, out_idx);
    vq_zq_loss<<<NLOSS_BLOCKS, 256, 0, stream>>>(z, cb, out_idx, out, parts);
    vq_finalize_scalars<<<1, 256, 0, stream>>>(parts, out_idx, out);
    hipMemsetAsync(encb, 0, ENC_BYTES, stream);
    vq_scatter<<<64, 256, 0, stream>>>(out_idx, enc);
}